// Round 16
// baseline (24.452 us; speedup 1.0000x reference)
//
#include <hip/hip_runtime.h>
#include <math.h>

// PAM module: B=8, C=64, CQ=8, N=2048
// out[b,c,i] = gamma * sum_j softmax_j(q[i,:]·k[:,j]) * v[c,j] + x[b,c,i]
//
// ws layouts (bf16), in MFMA-fragment order so attn loads are contiguous:
//  Q[b][ib(128)][half(2)][li(16)][e(8)]            (32768/batch)
//  K[b][t(32)][f(4)][half(2)][m(16)][e(8)]         (32768/batch)
//     K row for j = t*64 + jl stored at f = (jl>>5) + 2*((jl>>2)&1),
//     m = ((jl>>3)&3)*4 + (jl&3)  -> QK output lane (li,g) then holds
//     P[li][jc*32 + g*8 + 0..7] == the PV B-fragment of that SAME lane.
//  V[b][t(32)][jc(2)][cb(4)][li(16)][g(4)][e(8)]   (131072/batch) j=t*64+jc*32+g*8+e, c=cb*16+li
//
// attn v16 = v15 + 1-step software pipeline: PV(t) consumes pk/vc produced
// at step t-1, so QK(t+1) MFMAs, PV(t) MFMAs, V(t+1) loads and exp2(t+1)
// are mutually independent inside an iteration. Grid-limited 1 block/CU ->
// the extra stage registers are free (VGPR budget 256 under (512,2)).

#define NB  8
#define NC  64
#define NN  2048
#define L2E 1.44269504088896340736f
#define MST 36          // merge acc stride (floats per lane)

typedef float f32x4 __attribute__((ext_vector_type(4)));
typedef __bf16 bf16x8 __attribute__((ext_vector_type(8)));
typedef __bf16 bf16x2 __attribute__((ext_vector_type(2)));
typedef unsigned short ushort_t;
typedef unsigned short us4 __attribute__((ext_vector_type(4)));

__device__ __forceinline__ unsigned short f2bf(float f) {
    unsigned u = __float_as_uint(f);
    u += 0x7fffu + ((u >> 16) & 1u);          // RNE
    return (unsigned short)(u >> 16);
}
__device__ __forceinline__ float bf2f(unsigned short h) {
    return __uint_as_float(((unsigned)h) << 16);
}
__device__ __forceinline__ unsigned packbf(float a, float b) {
    union { bf16x2 v; unsigned u; } t;
    t.v = (bf16x2){ (__bf16)a, (__bf16)b };
    return t.u;
}

// ---------------- QKV projection v5 (K j-permuted store, unchanged) -------
__global__ __launch_bounds__(256) void qkv_kernel(
    const float* __restrict__ x,
    const float* __restrict__ Wq, const float* __restrict__ bq,
    const float* __restrict__ Wk, const float* __restrict__ bk,
    const float* __restrict__ Wv, const float* __restrict__ bv,
    ushort_t* __restrict__ Qws, ushort_t* __restrict__ Kws,
    ushort_t* __restrict__ Vws)
{
    __shared__ float sWg[64][20];
    __shared__ float sB[16];
    __shared__ float sX[64][64];

    const int tid = threadIdx.x;
    const unsigned blk = blockIdx.x;
    const int b = blk & 7;
    const unsigned rest = blk >> 3;
    const unsigned pc = rest / 5u;
    const int og = (int)(rest - pc * 5u);
    const int n0 = (int)pc * 64;
    const int obase = og * 16;

    for (int idx = tid; idx < 1024; idx += 256) {
        const int o = idx >> 6;
        const int c = idx & 63;
        const int oo = obase + o;
        float w;
        if (oo < 8)       w = Wq[oo * NC + c] * L2E;
        else if (oo < 16) w = Wk[(oo - 8) * NC + c];
        else              w = Wv[(oo - 16) * NC + c];
        sWg[c][o] = w;
    }
    if (tid < 16) {
        const int oo = obase + tid;
        float v;
        if (oo < 8)       v = bq[oo] * L2E;
        else if (oo < 16) v = bk[oo - 8];
        else              v = bv[oo - 16];
        sB[tid] = v;
    }
    {
        const float* xg = x + (size_t)b * NC * NN + n0;
        for (int idx = tid; idx < 4096; idx += 256) {
            const int c = idx >> 6, px = idx & 63;
            sX[c][px] = xg[(size_t)c * NN + px];
        }
    }
    __syncthreads();

    const int lanepx = tid & 63;
    const int wv = tid >> 6;

    f32x4 acc = { sB[wv*4+0], sB[wv*4+1], sB[wv*4+2], sB[wv*4+3] };
    #pragma unroll
    for (int ch = 0; ch < 64; ch++) {
        const float xv = sX[ch][lanepx];
        const f32x4 w = *(const f32x4*)&sWg[ch][wv * 4];
        acc[0] = fmaf(w[0], xv, acc[0]);
        acc[1] = fmaf(w[1], xv, acc[1]);
        acc[2] = fmaf(w[2], xv, acc[2]);
        acc[3] = fmaf(w[3], xv, acc[3]);
    }

    const int n = n0 + lanepx;
    const int t  = n >> 6;

    if (og == 0) {
        us4 hi, lo;
        #pragma unroll
        for (int e = 0; e < 4; e++) {
            const unsigned short h = f2bf(acc[e]);
            hi[e] = h;
            lo[e] = f2bf(acc[e] - bf2f(h));
        }
        if (wv < 2) {
            // Q: [b][ib][half][li][8]
            const size_t a = (size_t)b * 32768 + (size_t)(n >> 4) * 256
                           + (size_t)(n & 15) * 8 + wv * 4;
            *(us4*)(Qws + a)       = hi;
            *(us4*)(Qws + a + 128) = lo;
        } else {
            // K: j-permuted store so PV B-frag is lane-local in attn
            const int jl = n & 63;
            const int fK = ((jl >> 5) & 1) + 2 * ((jl >> 2) & 1);
            const int mK = ((jl >> 3) & 3) * 4 + (jl & 3);
            const size_t a = (size_t)b * 32768 + (size_t)t * 1024
                           + (size_t)fK * 256 + (size_t)mK * 8 + (wv - 2) * 4;
            *(us4*)(Kws + a)       = hi;
            *(us4*)(Kws + a + 128) = lo;
        }
    } else {
        const int jc = (n >> 5) & 1;
        const int gg = (n >> 3) & 3;
        const int e8 = n & 7;
        const int cb = og - 1;
        const size_t base = (size_t)b * 131072 + (size_t)t * 4096
                          + (size_t)jc * 2048 + (size_t)cb * 512
                          + (size_t)gg * 8 + e8;
        #pragma unroll
        for (int e = 0; e < 4; e++)
            Vws[base + (size_t)(wv * 4 + e) * 32] = f2bf(acc[e]);
    }
}

// ---------------- fused flash attention v16 (software-pipelined) ----------
// 256 blocks = 8 b x 32 rb (1 block/CU); 512 threads = 8 waves = 2 rg x 4 jq.
// Wave: 32 rows (2 i-blocks) x 512 j (8 steps of 64); PV deferred 1 step.
__global__ __launch_bounds__(512, 2) void attn_kernel(
    const ushort_t* __restrict__ Qg, const ushort_t* __restrict__ Kg,
    const ushort_t* __restrict__ Vg, const float* __restrict__ x,
    const float* __restrict__ gamma, float* __restrict__ out)
{
    __shared__ __align__(16) char smem[74752];
    float* sMacc = (float*)smem;               // [8*64 lanes][MST]
    float* sMl   = (float*)(smem + 73728);     // [8*32 rows]

    const int tid  = threadIdx.x;
    const int w    = tid >> 6;          // 0..7
    const int rg   = w >> 2;            // row-group 0..1
    const int jq   = w & 3;             // j-quarter 0..3
    const int lane = tid & 63;
    const int li   = lane & 15;
    const int g    = lane >> 4;
    const int b    = blockIdx.x & 7;    // batch -> XCD
    const int rb   = blockIdx.x >> 3;   // 0..31
    const int i0   = rb * 64 + rg * 32;

    const ushort_t* Kb = Kg + (size_t)b * 32768;
    const ushort_t* Vb = Vg + (size_t)b * 131072;

    const int ib0 = rb * 4 + rg * 2;
    const bf16x8 qf0 = *(const bf16x8*)(Qg + (size_t)b * 32768 + (size_t)ib0 * 256
                                        + (size_t)(g & 1) * 128 + (size_t)li * 8);
    const bf16x8 qf1 = *(const bf16x8*)(Qg + (size_t)b * 32768 + (size_t)(ib0 + 1) * 256
                                        + (size_t)(g & 1) * 128 + (size_t)li * 8);

    float l0 = 0.f, l1 = 0.f;
    f32x4 acc0[4], acc1[4];
    #pragma unroll
    for (int cb = 0; cb < 4; cb++) {
        acc0[cb] = (f32x4){0.f,0.f,0.f,0.f};
        acc1[cb] = (f32x4){0.f,0.f,0.f,0.f};
    }
    const f32x4 zero4 = {0.f,0.f,0.f,0.f};

    const ushort_t* Kq = Kb + (size_t)(jq * 8) * 1024 + (size_t)(g >> 1) * 128 + (size_t)li * 8;
    const ushort_t* Vq = Vb + (size_t)(jq * 8) * 4096 + (size_t)li * 32 + (size_t)g * 8;

    // pipeline state: kc = K(t+1) frags; vcA = V(t) frags; pkP = P(t) packed
    bf16x8 kc[4], vcA[8];
    unsigned pkP[16];   // [0..3]=A0, [4..7]=B0, [8..11]=A1, [12..15]=B1

    #pragma unroll
    for (int f = 0; f < 4; f++) kc[f] = *(const bf16x8*)(Kq + (size_t)f * 256);
    #pragma unroll
    for (int u = 0; u < 8; u++)
        vcA[u] = *(const bf16x8*)(Vq + (size_t)(u >> 2) * 2048 + (size_t)(u & 3) * 512);

    // ---- prologue: P(0) ----
    {
        f32x4 e0[4], e1[4];
        __builtin_amdgcn_s_setprio(1);
        #pragma unroll
        for (int f = 0; f < 4; f++)
            e0[f] = __builtin_amdgcn_mfma_f32_16x16x32_bf16(kc[f], qf0, zero4, 0, 0, 0);
        #pragma unroll
        for (int f = 0; f < 4; f++)
            e1[f] = __builtin_amdgcn_mfma_f32_16x16x32_bf16(kc[f], qf1, zero4, 0, 0, 0);
        __builtin_amdgcn_s_setprio(0);
        #pragma unroll
        for (int f = 0; f < 4; f++)
            kc[f] = *(const bf16x8*)(Kq + 1024 + (size_t)f * 256);
        float ls0 = 0.f, ls1 = 0.f;
        #pragma unroll
        for (int f = 0; f < 4; f++) {
            const float a0 = __builtin_amdgcn_exp2f(e0[f][0]);
            const float a1 = __builtin_amdgcn_exp2f(e0[f][1]);
            const float a2 = __builtin_amdgcn_exp2f(e0[f][2]);
            const float a3 = __builtin_amdgcn_exp2f(e0[f][3]);
            pkP[f]     = packbf(a0, a1);
            pkP[4 + f] = packbf(a2, a3);
            ls0 += (a0 + a1) + (a2 + a3);
            const float c0 = __builtin_amdgcn_exp2f(e1[f][0]);
            const float c1 = __builtin_amdgcn_exp2f(e1[f][1]);
            const float c2 = __builtin_amdgcn_exp2f(e1[f][2]);
            const float c3 = __builtin_amdgcn_exp2f(e1[f][3]);
            pkP[8 + f]  = packbf(c0, c1);
            pkP[12 + f] = packbf(c2, c3);
            ls1 += (c0 + c1) + (c2 + c3);
        }
        l0 += ls0; l1 += ls1;
    }

    // ---- main pipelined loop: iter t does QK/P(t+1) and PV(t) ----
    #pragma unroll
    for (int t = 0; t < 7; ++t) {
        // V(t+1) loads (consumed by PV next iteration)
        bf16x8 vcB[8];
        #pragma unroll
        for (int u = 0; u < 8; u++)
            vcB[u] = *(const bf16x8*)(Vq + (size_t)(t + 1) * 4096
                                      + (size_t)(u >> 2) * 2048 + (size_t)(u & 3) * 512);

        // QK(t+1)
        f32x4 e0[4], e1[4];
        __builtin_amdgcn_s_setprio(1);
        #pragma unroll
        for (int f = 0; f < 4; f++)
            e0[f] = __builtin_amdgcn_mfma_f32_16x16x32_bf16(kc[f], qf0, zero4, 0, 0, 0);
        #pragma unroll
        for (int f = 0; f < 4; f++)
            e1[f] = __builtin_amdgcn_mfma_f32_16x16x32_bf16(kc[f], qf1, zero4, 0, 0, 0);

        // PV(t): independent of QK above (covers the e->exp2 latency)
        {
            union { unsigned u[4]; bf16x8 v; } pf0, pf1;
            pf0.u[0] = pkP[0]; pf0.u[1] = pkP[4]; pf0.u[2] = pkP[2]; pf0.u[3] = pkP[6];
            pf1.u[0] = pkP[8]; pf1.u[1] = pkP[12]; pf1.u[2] = pkP[10]; pf1.u[3] = pkP[14];
            #pragma unroll
            for (int cb = 0; cb < 4; cb++) {
                acc0[cb] = __builtin_amdgcn_mfma_f32_16x16x32_bf16(vcA[cb], pf0.v, acc0[cb], 0, 0, 0);
                acc1[cb] = __builtin_amdgcn_mfma_f32_16x16x32_bf16(vcA[cb], pf1.v, acc1[cb], 0, 0, 0);
            }
            pf0.u[0] = pkP[1]; pf0.u[1] = pkP[5]; pf0.u[2] = pkP[3]; pf0.u[3] = pkP[7];
            pf1.u[0] = pkP[9]; pf1.u[1] = pkP[13]; pf1.u[2] = pkP[11]; pf1.u[3] = pkP[15];
            #pragma unroll
            for (int cb = 0; cb < 4; cb++) {
                acc0[cb] = __builtin_amdgcn_mfma_f32_16x16x32_bf16(vcA[4 + cb], pf0.v, acc0[cb], 0, 0, 0);
                acc1[cb] = __builtin_amdgcn_mfma_f32_16x16x32_bf16(vcA[4 + cb], pf1.v, acc1[cb], 0, 0, 0);
            }
        }
        __builtin_amdgcn_s_setprio(0);

        // K(t+2) prefetch
        if (t < 6) {
            #pragma unroll
            for (int f = 0; f < 4; f++)
                kc[f] = *(const bf16x8*)(Kq + (size_t)(t + 2) * 1024 + (size_t)f * 256);
        }

        // P(t+1): exp2 on the VALU while PV MFMAs drain
        float ls0 = 0.f, ls1 = 0.f;
        #pragma unroll
        for (int f = 0; f < 4; f++) {
            const float a0 = __builtin_amdgcn_exp2f(e0[f][0]);
            const float a1 = __builtin_amdgcn_exp2f(e0[f][1]);
            const float a2 = __builtin_amdgcn_exp2f(e0[f][2]);
            const float a3 = __builtin_amdgcn_exp2f(e0[f][3]);
            pkP[f]     = packbf(a0, a1);
            pkP[4 + f] = packbf(a2, a3);
            ls0 += (a0 + a1) + (a2 + a3);
            const float c0 = __builtin_amdgcn_exp2f(e1[f][0]);
            const float c1 = __builtin_amdgcn_exp2f(e1[f][1]);
            const float c2 = __builtin_amdgcn_exp2f(e1[f][2]);
            const float c3 = __builtin_amdgcn_exp2f(e1[f][3]);
            pkP[8 + f]  = packbf(c0, c1);
            pkP[12 + f] = packbf(c2, c3);
            ls1 += (c0 + c1) + (c2 + c3);
        }
        l0 += ls0; l1 += ls1;

        // rotate V stage (register renaming under full unroll)
        #pragma unroll
        for (int u = 0; u < 8; u++) vcA[u] = vcB[u];
    }

    // ---- epilogue: PV(7) ----
    {
        union { unsigned u[4]; bf16x8 v; } pf0, pf1;
        __builtin_amdgcn_s_setprio(1);
        pf0.u[0] = pkP[0]; pf0.u[1] = pkP[4]; pf0.u[2] = pkP[2]; pf0.u[3] = pkP[6];
        pf1.u[0] = pkP[8]; pf1.u[1] = pkP[12]; pf1.u[2] = pkP[10]; pf1.u[3] = pkP[14];
        #pragma unroll
        for (int cb = 0; cb < 4; cb++) {
            acc0[cb] = __builtin_amdgcn_mfma_f32_16x16x32_bf16(vcA[cb], pf0.v, acc0[cb], 0, 0, 0);
            acc1[cb] = __builtin_amdgcn_mfma_f32_16x16x32_bf16(vcA[cb], pf1.v, acc1[cb], 0, 0, 0);
        }
        pf0.u[0] = pkP[1]; pf0.u[1] = pkP[5]; pf0.u[2] = pkP[3]; pf0.u[3] = pkP[7];
        pf1.u[0] = pkP[9]; pf1.u[1] = pkP[13]; pf1.u[2] = pkP[11]; pf1.u[3] = pkP[15];
        #pragma unroll
        for (int cb = 0; cb < 4; cb++) {
            acc0[cb] = __builtin_amdgcn_mfma_f32_16x16x32_bf16(vcA[4 + cb], pf0.v, acc0[cb], 0, 0, 0);
            acc1[cb] = __builtin_amdgcn_mfma_f32_16x16x32_bf16(vcA[4 + cb], pf1.v, acc1[cb], 0, 0, 0);
        }
        __builtin_amdgcn_s_setprio(0);
    }

    // row-total l across the 4 g-lanes
    l0 += __shfl_xor(l0, 16); l0 += __shfl_xor(l0, 32);
    l1 += __shfl_xor(l1, 16); l1 += __shfl_xor(l1, 32);

    // ---- per-rg 4-way merge (plain sums) ----
    __syncthreads();
    {
        float* ap = sMacc + (size_t)(w * 64 + lane) * MST;
        #pragma unroll
        for (int cb = 0; cb < 4; cb++) {
            *(f32x4*)(ap + cb * 4)      = acc0[cb];
            *(f32x4*)(ap + 16 + cb * 4) = acc1[cb];
        }
        if (g == 0) {
            sMl[w * 32 + li]      = l0;
            sMl[w * 32 + 16 + li] = l1;
        }
    }
    __syncthreads();

    {
        const int r = lane & 31;
        const float gmv = gamma[0];
        #pragma unroll
        for (int u = 0; u < 2; u++) {
            const int cq   = jq * 4 + (lane >> 5) * 2 + u;   // 0..15
            const int g_s  = cq & 3;
            const int cb_s = cq >> 2;
            const int ib_s = r >> 4;
            const int li_s = r & 15;
            const int srcln = g_s * 16 + li_s;
            const int aidx  = ib_s * 16 + cb_s * 4;

            float L = 0.f;
            float num0 = 0.f, num1 = 0.f, num2 = 0.f, num3 = 0.f;
            #pragma unroll
            for (int q = 0; q < 4; q++) {
                const int w2 = rg * 4 + q;
                L += sMl[w2 * 32 + r];
                const f32x4 a = *(const f32x4*)(sMacc + (size_t)(w2 * 64 + srcln) * MST + aidx);
                num0 += a[0]; num1 += a[1]; num2 += a[2]; num3 += a[3];
            }
            const float inv = 1.0f / L;
            const size_t gb = (size_t)b * NC * NN + i0 + r;
            const size_t c0 = (size_t)cq * 4;
            out[gb + (c0 + 0) * NN] = fmaf(gmv, num0 * inv, x[gb + (c0 + 0) * NN]);
            out[gb + (c0 + 1) * NN] = fmaf(gmv, num1 * inv, x[gb + (c0 + 1) * NN]);
            out[gb + (c0 + 2) * NN] = fmaf(gmv, num2 * inv, x[gb + (c0 + 2) * NN]);
            out[gb + (c0 + 3) * NN] = fmaf(gmv, num3 * inv, x[gb + (c0 + 3) * NN]);
        }
    }
}

extern "C" void kernel_launch(void* const* d_in, const int* in_sizes, int n_in,
                              void* d_out, int out_size, void* d_ws, size_t ws_size,
                              hipStream_t stream) {
    const float* x     = (const float*)d_in[0];
    const float* Wq    = (const float*)d_in[1];
    const float* bq    = (const float*)d_in[2];
    const float* Wk    = (const float*)d_in[3];
    const float* bk    = (const float*)d_in[4];
    const float* Wv    = (const float*)d_in[5];
    const float* bv    = (const float*)d_in[6];
    const float* gamma = (const float*)d_in[7];
    float* out = (float*)d_out;

    // ws (ushorts): Q 8*32768 | K 8*32768 | V 8*131072  (3 MB total)
    ushort_t* Qws = (ushort_t*)d_ws;
    ushort_t* Kws = Qws + (size_t)NB * 32768;
    ushort_t* Vws = Kws + (size_t)NB * 32768;

    qkv_kernel<<<1280, 256, 0, stream>>>(x, Wq, bq, Wk, bk, Wv, bv, Qws, Kws, Vws);
    attn_kernel<<<NB * 32, 512, 0, stream>>>(Qws, Kws, Vws, x, gamma, out);
}